// Round 3
// baseline (633.646 us; speedup 1.0000x reference)
//
#include <hip/hip_runtime.h>
#include <stdint.h>

typedef unsigned short u16;
typedef unsigned int   u32;

#define B_SZ  32
#define CIN   256
#define NPIX  3136      // 56*56
#define COUT  256
#define HID   64
#define NBANK 4
#define BANK_SZ 589824  // COUT*CIN*9 per bank (fp32 elements)
#define WF_N  18874368  // premixed elements per half: 32*8*9*8*2*512
#define XT_N  25690112  // pre-split x elements per half: 32*3136*256
#define XS_PLANE 11136  // LDS u16 per plane: 348 positions * 32 ci

typedef short bf16x8 __attribute__((ext_vector_type(8)));
typedef float f32x4  __attribute__((ext_vector_type(4)));
typedef float f32x16 __attribute__((ext_vector_type(16)));

struct __align__(16) U4 { u32 x, y, z, w; };
struct __align__(16) F4 { float x, y, z, w; };

__device__ __forceinline__ float bf2f(u16 u) {
    union { u32 i; float f; } v; v.i = ((u32)u) << 16; return v.f;
}
__device__ __forceinline__ u16 f2bf(float f) {
    union { float f; u32 i; } v; v.f = f;
    u32 u = v.i;
    return (u16)((u + 0x7FFFu + ((u >> 16) & 1u)) >> 16);   // RNE
}
// async global->LDS, 16B per lane; lptr must be wave-uniform (HW adds lane*16)
__device__ __forceinline__ void dma16(const u16* g, const u16* l) {
    __builtin_amdgcn_global_load_lds(
        (const __attribute__((address_space(1))) void*)g,
        (__attribute__((address_space(3))) void*)l, 16, 0, 0);
}

// ---------------------------------------------------------------- zero ----
__global__ __launch_bounds__(256) void k_zero(float* __restrict__ v) {
    v[blockIdx.x * 256 + threadIdx.x] = 0.f;   // grid 32 x 256 = 8192 floats
}

// --------------------------------------------------------------- split ----
// x fp32 [b][ci][pix] -> xt_h/xt_l bf16 [b][pix][ci]; also mean partials.
// grid (49 pix-tiles, 4 ci-chunks of 64, 32 b), 256 thr. LDS 64x65 fp32.
__global__ __launch_bounds__(256) void k_split(const float* __restrict__ x,
        u16* __restrict__ xt, float* __restrict__ vout) {
    const int ptile = blockIdx.x, cchunk = blockIdx.y, b = blockIdx.z;
    const int pix0 = ptile * 64, ci0 = cchunk * 64;
    const int t = threadIdx.x, lane = t & 63, w = t >> 6;
    __shared__ float ls[64 * 65];
    const float* xb = x + ((size_t)b * CIN + ci0) * NPIX + pix0;
    float psum[16];
    #pragma unroll
    for (int r = 0; r < 16; ++r) {
        int ci_l = r * 4 + w;
        float v = xb[(size_t)ci_l * NPIX + lane];
        ls[ci_l * 65 + lane] = v;
        psum[r] = v;
    }
    #pragma unroll
    for (int r = 0; r < 16; ++r) {
        float s = psum[r];
        #pragma unroll
        for (int off = 32; off > 0; off >>= 1) s += __shfl_down(s, off, 64);
        if (lane == 0)
            atomicAdd(&vout[b * CIN + ci0 + r * 4 + w], s * (1.0f / 3136.0f));
    }
    __syncthreads();
    u16* xth = xt + ((size_t)b * NPIX + pix0) * 256 + ci0;
    #pragma unroll
    for (int rep = 0; rep < 2; ++rep) {
        int item = rep * 256 + t;
        int pix_l = item >> 3, o8 = item & 7;
        u16 eh[8], el[8];
        #pragma unroll
        for (int q = 0; q < 8; ++q) {
            float v = ls[(o8 * 8 + q) * 65 + pix_l];
            u16 h = f2bf(v);
            eh[q] = h;
            el[q] = f2bf(v - bf2f(h));
        }
        U4 uh, ul;
        uh.x = (u32)eh[0] | ((u32)eh[1] << 16);
        uh.y = (u32)eh[2] | ((u32)eh[3] << 16);
        uh.z = (u32)eh[4] | ((u32)eh[5] << 16);
        uh.w = (u32)eh[6] | ((u32)eh[7] << 16);
        ul.x = (u32)el[0] | ((u32)el[1] << 16);
        ul.y = (u32)el[2] | ((u32)el[3] << 16);
        ul.z = (u32)el[4] | ((u32)el[5] << 16);
        ul.w = (u32)el[6] | ((u32)el[7] << 16);
        *(U4*)(xth + (size_t)pix_l * 256 + o8 * 8)        = uh;
        *(U4*)(xth + XT_N + (size_t)pix_l * 256 + o8 * 8) = ul;
    }
}

// ---------------------------------------------------------------- mean ----
// fallback-path mean (used when ws too small for k_split outputs)
__global__ __launch_bounds__(64) void k_mean(const float* __restrict__ x,
                                             float* __restrict__ vout) {
    int bc = blockIdx.x;
    const F4* p = (const F4*)(x + (size_t)bc * NPIX);
    float s = 0.f;
    for (int o = threadIdx.x; o < 784; o += 64) {
        F4 u = p[o];
        s += u.x + u.y + u.z + u.w;
    }
    #pragma unroll
    for (int off = 32; off > 0; off >>= 1) s += __shfl_down(s, off, 64);
    if (threadIdx.x == 0) vout[bc] = s * (1.0f / 3136.0f);
}

// -------------------------------------------------------------- router ----
__global__ __launch_bounds__(64) void k_router(const float* __restrict__ v,
        const float* __restrict__ fc1w, const float* __restrict__ fc1b,
        const float* __restrict__ fc2w, const float* __restrict__ fc2b,
        float* __restrict__ aout) {
    int b = blockIdx.x, j = threadIdx.x;
    __shared__ float hl[HID];
    __shared__ float lg[NBANK];
    const float* vb = v + b * CIN;
    float acc = fc1b[j];
    const F4* wrow = (const F4*)(fc1w + j * CIN);
    for (int o = 0; o < 64; ++o) {
        F4 u = wrow[o];
        acc += vb[o * 4 + 0] * u.x + vb[o * 4 + 1] * u.y
             + vb[o * 4 + 2] * u.z + vb[o * 4 + 3] * u.w;
    }
    hl[j] = acc > 0.f ? acc : 0.f;
    __syncthreads();
    if (j < NBANK) {
        float l = fc2b[j];
        for (int t = 0; t < HID; ++t) l += hl[t] * fc2w[j * HID + t];
        lg[j] = l;
    }
    __syncthreads();
    if (j == 0) {
        float m = lg[0];
        for (int k = 1; k < NBANK; ++k) m = fmaxf(m, lg[k]);
        float e[NBANK], se = 0.f;
        for (int k = 0; k < NBANK; ++k) { e[k] = expf(lg[k] - m); se += e[k]; }
        for (int k = 0; k < NBANK; ++k) aout[b * NBANK + k] = e[k] / se;
    }
}

// -------------------------------------------------------------- premix ----
// Wdyn = sum_k a[b][k]*bank[k], fp32 mix -> bf16 hi/lo, stored in 32x32x16
// MFMA-A layout: wf[half][b][cof32][t][cis][kc][lane][8]
//   co = cof32*32 + (lane&31); ci = cis*32 + kc*16 + (lane>>5)*8 + jj
// grid = 128 blocks (cof32 in [0,8), cis16 in [0,16)), 256 threads.
#define PMP 145
__global__ __launch_bounds__(256) void k_premix(const float* __restrict__ bank,
        const float* __restrict__ aws, u16* __restrict__ wf) {
    const int cof   = blockIdx.x >> 4;   // 0..7
    const int cis16 = blockIdx.x & 15;   // 0..15 (16-ci granule)
    __shared__ float lw[128 * PMP];      // [k*32+co_l][ci_l16*9 + t]
    for (int idx = threadIdx.x; idx < 128 * 144; idx += 256) {
        int s = idx / 144;               // k*32 + co_l
        int e = idx - s * 144;
        int k = s >> 5, co_l = s & 31;
        lw[s * PMP + e] =
            bank[(size_t)(k * COUT + cof * 32 + co_l) * (CIN * 9) + cis16 * 144 + e];
    }
    __syncthreads();
    const int kc = cis16 & 1, cis = cis16 >> 1;
    for (int b = 0; b < B_SZ; ++b) {
        float a0 = aws[b * 4 + 0], a1 = aws[b * 4 + 1];
        float a2 = aws[b * 4 + 2], a3 = aws[b * 4 + 3];
        for (int o = threadIdx.x; o < 576; o += 256) {   // 9 taps * 64 lanes
            int t = o >> 6, lane = o & 63;
            int m = lane & 31, h5 = lane >> 5;
            u16 ph[8], plo[8];
            #pragma unroll
            for (int jj = 0; jj < 8; ++jj) {
                int ee = (h5 * 8 + jj) * 9 + t;
                float w = a0 * lw[(0 * 32 + m) * PMP + ee]
                        + a1 * lw[(1 * 32 + m) * PMP + ee]
                        + a2 * lw[(2 * 32 + m) * PMP + ee]
                        + a3 * lw[(3 * 32 + m) * PMP + ee];
                u16 h = f2bf(w);
                ph[jj]  = h;
                plo[jj] = f2bf(w - bf2f(h));
            }
            size_t off = ((((size_t)b * 8 + cof) * 9 + t) * 8 + cis) * 1024
                       + (size_t)kc * 512 + (size_t)lane * 8;
            U4 uh, ul;
            uh.x = (u32)ph[0] | ((u32)ph[1] << 16);
            uh.y = (u32)ph[2] | ((u32)ph[3] << 16);
            uh.z = (u32)ph[4] | ((u32)ph[5] << 16);
            uh.w = (u32)ph[6] | ((u32)ph[7] << 16);
            ul.x = (u32)plo[0] | ((u32)plo[1] << 16);
            ul.y = (u32)plo[2] | ((u32)plo[3] << 16);
            ul.z = (u32)plo[4] | ((u32)plo[5] << 16);
            ul.w = (u32)plo[6] | ((u32)plo[7] << 16);
            *(U4*)(wf + off)        = uh;
            *(U4*)(wf + WF_N + off) = ul;
        }
    }
}

// ---------------------------------------------------------------- conv ----
// Implicit GEMM, split-bf16 3-pass: y ~= wh*xh + wh*xl + wl*xh (fp32 acc).
// mfma_f32_32x32x16_bf16. Block 256 thr = 4 waves (2x2 over co x pix),
// block tile 128co x 128pix; per wave 64co x 64pix = 2mf x 2nf f32x16 acc.
// LDS: xh/xl planes [348 pos][32 ci] bf16 = 44544 B; slot = item*16B with
// octet XOR-swizzle (bank spread); SPLIT: filled by global_load_lds DMA from
// pre-split xt, OOB halo pre-zeroed once. !SPLIT: in-kernel fp32 split.
template<bool SPLIT>
__global__ __launch_bounds__(256, 2) void k_conv(const float* __restrict__ x,
        const u16* __restrict__ xt,       // pre-split hi; lo at +XT_N
        const u16* __restrict__ wf,       // premixed hi; lo at +WF_N
        float* __restrict__ out) {
    const int pt    = blockIdx.x;   // 0..24 pixel tile (128 px)
    const int coblk = blockIdx.y;   // 0..1  co half (128 co)
    const int b     = blockIdx.z;   // 0..31

    const int tid  = threadIdx.x;
    const int wave = tid >> 6;
    const int lane = tid & 63;
    const int wm = wave >> 1, wn = wave & 1;
    const int m5 = lane & 31, h5 = lane >> 5;

    __shared__ u16 xs[2 * XS_PLANE];   // hi, lo planes

    const int pix0 = pt * 128;
    const int h0   = pix0 / 56;
    const int rlo  = h0 - 1;

    // pre-zero OOB halo slots once (staging never writes them)
    for (int rc = tid; rc < 348; rc += 256) {
        int row = rc / 58, col = rc - row * 58;
        int hin = rlo + row, win = col - 1;
        if (!((unsigned)hin < 56u && (unsigned)win < 56u)) {
            U4 z; z.x = z.y = z.z = z.w = 0;
            #pragma unroll
            for (int o = 0; o < 4; ++o) {
                *(U4*)(&xs[rc * 32 + o * 8])            = z;
                *(U4*)(&xs[XS_PLANE + rc * 32 + o * 8]) = z;
            }
        }
    }

    // per-lane B pixel info (nf covers pixels +0, +32)
    int rcb[2], pl[2];
    #pragma unroll
    for (int nf = 0; nf < 2; ++nf) {
        int p = pix0 + wn * 64 + nf * 32 + m5;
        pl[nf] = p;
        int pc = p < NPIX ? p : NPIX - 1;
        int hp = pc / 56, wp = pc - (pc / 56) * 56;
        rcb[nf] = (hp - h0) * 58 + wp;
    }

    const int cof_base = coblk * 4 + wm * 2;
    const u16* xth = xt + (size_t)b * (NPIX * 256);
    const u16* xtl = xth + XT_N;
    const float* xb = x + (size_t)b * CIN * NPIX;

    f32x16 acc[2][2];
    #pragma unroll
    for (int i = 0; i < 2; ++i)
        #pragma unroll
        for (int j = 0; j < 2; ++j)
            #pragma unroll
            for (int r = 0; r < 16; ++r) acc[i][j][r] = 0.f;

    for (int cis = 0; cis < 8; ++cis) {
        __syncthreads();   // prev readers done (and iter0: zero-writes visible)
        if (SPLIT) {
            // DMA: 1392 items (348 pos x 4 octets), 16B each; slot = item*16
            for (int it = wave; it < 22; it += 4) {
                int item = it * 64 + lane;
                int pos  = item >> 2;
                int soct = item & 3;
                int goct = soct ^ (pos & 3);          // content swizzle
                int row = pos / 58, col = pos - (pos / 58) * 58;
                int hin = rlo + row, win = col - 1;
                bool ok = (item < 1392) &&
                          ((unsigned)hin < 56u) && ((unsigned)win < 56u);
                if (ok) {
                    size_t gb = (size_t)((hin * 56 + win) * 256 + cis * 32 + goct * 8);
                    dma16(xth + gb, &xs[it * 512]);              // hi plane
                    dma16(xtl + gb, &xs[XS_PLANE + it * 512]);   // lo plane
                }
            }
        } else {
            for (int idx = tid; idx < 1392; idx += 256) {
                int pos  = idx >> 2;
                int soct = idx & 3;
                int goct = soct ^ (pos & 3);
                int row = pos / 58, col = pos - (pos / 58) * 58;
                int hin = rlo + row, win = col - 1;
                if ((unsigned)hin < 56u && (unsigned)win < 56u) {
                    const float* g = xb + (size_t)(cis * 32 + goct * 8) * NPIX
                                   + hin * 56 + win;
                    u16 eh[8], el[8];
                    #pragma unroll
                    for (int i = 0; i < 8; ++i) {
                        float v = g[(size_t)i * NPIX];
                        u16 h = f2bf(v);
                        eh[i] = h;
                        el[i] = f2bf(v - bf2f(h));
                    }
                    U4 uh, ul;
                    uh.x = (u32)eh[0] | ((u32)eh[1] << 16);
                    uh.y = (u32)eh[2] | ((u32)eh[3] << 16);
                    uh.z = (u32)eh[4] | ((u32)eh[5] << 16);
                    uh.w = (u32)eh[6] | ((u32)eh[7] << 16);
                    ul.x = (u32)el[0] | ((u32)el[1] << 16);
                    ul.y = (u32)el[2] | ((u32)el[3] << 16);
                    ul.z = (u32)el[4] | ((u32)el[5] << 16);
                    ul.w = (u32)el[6] | ((u32)el[7] << 16);
                    *(U4*)(&xs[idx * 8])            = uh;
                    *(U4*)(&xs[XS_PLANE + idx * 8]) = ul;
                }
            }
        }
        __syncthreads();   // DMA drained (vmcnt) / writes visible

        #pragma unroll
        for (int t = 0; t < 9; ++t) {
            const int ty = t / 3, tx = t - (t / 3) * 3;
            bf16x8 ah[2][2], al[2][2];
            #pragma unroll
            for (int mf = 0; mf < 2; ++mf)
                #pragma unroll
                for (int kc = 0; kc < 2; ++kc) {
                    size_t off = ((((size_t)b * 8 + cof_base + mf) * 9 + t) * 8 + cis) * 1024
                               + (size_t)kc * 512 + (size_t)lane * 8;
                    ah[mf][kc] = *(const bf16x8*)(wf + off);
                    al[mf][kc] = *(const bf16x8*)(wf + WF_N + off);
                }
            #pragma unroll
            for (int nf = 0; nf < 2; ++nf) {
                int rc = rcb[nf] + ty * 58 + tx;
                int sw = rc & 3;
                int base = rc * 32;
                #pragma unroll
                for (int kc = 0; kc < 2; ++kc) {
                    int oct  = kc * 2 + h5;
                    int eoff = base + ((oct ^ sw) * 8);
                    bf16x8 bh = *(const bf16x8*)(&xs[eoff]);
                    bf16x8 bl = *(const bf16x8*)(&xs[XS_PLANE + eoff]);
                    #pragma unroll
                    for (int mf = 0; mf < 2; ++mf) {
                        acc[mf][nf] = __builtin_amdgcn_mfma_f32_32x32x16_bf16(
                            ah[mf][kc], bh, acc[mf][nf], 0, 0, 0);
                        acc[mf][nf] = __builtin_amdgcn_mfma_f32_32x32x16_bf16(
                            ah[mf][kc], bl, acc[mf][nf], 0, 0, 0);
                        acc[mf][nf] = __builtin_amdgcn_mfma_f32_32x32x16_bf16(
                            al[mf][kc], bh, acc[mf][nf], 0, 0, 0);
                    }
                }
            }
        }
    }

    // epilogue: 32x32 C/D: col(pixel)=lane&31, row(co)=(r&3)+8*(r>>2)+4*(lane>>5)
    float* ob = out + (size_t)b * COUT * NPIX;
    #pragma unroll
    for (int mf = 0; mf < 2; ++mf) {
        int co0 = coblk * 128 + wm * 64 + mf * 32 + h5 * 4;
        #pragma unroll
        for (int nf = 0; nf < 2; ++nf) {
            int p = pl[nf];
            if (p < NPIX) {
                #pragma unroll
                for (int r = 0; r < 16; ++r) {
                    int co = co0 + (r & 3) + 8 * (r >> 2);
                    ob[(size_t)co * NPIX + p] = acc[mf][nf][r];
                }
            }
        }
    }
}

// -------------------------------------------------------------- launch ----
extern "C" void kernel_launch(void* const* d_in, const int* in_sizes, int n_in,
                              void* d_out, int out_size, void* d_ws, size_t ws_size,
                              hipStream_t stream) {
    const float* x    = (const float*)d_in[0];
    const float* bank = (const float*)d_in[1];
    const float* fc1w = (const float*)d_in[2];
    const float* fc1b = (const float*)d_in[3];
    const float* fc2w = (const float*)d_in[4];
    const float* fc2b = (const float*)d_in[5];
    float* out = (float*)d_out;

    float* a_ws = (float*)d_ws;                 // 128 floats
    float* v_ws = (float*)d_ws + 128;           // 8192 floats
    u16*   wf   = (u16*)((char*)d_ws + 65536);  // 75.5 MB premixed hi/lo
    u16*   xt   = (u16*)((char*)d_ws + 65536 + (size_t)WF_N * 4);  // 102.8 MB

    const size_t need_full = 65536 + (size_t)WF_N * 4 + (size_t)XT_N * 4;
    dim3 grid(25, 2, B_SZ);

    if (ws_size >= need_full) {
        k_zero  <<<dim3(32), dim3(256), 0, stream>>>(v_ws);
        k_split <<<dim3(49, 4, B_SZ), dim3(256), 0, stream>>>(x, xt, v_ws);
        k_router<<<dim3(B_SZ), dim3(64), 0, stream>>>(v_ws, fc1w, fc1b, fc2w, fc2b, a_ws);
        k_premix<<<dim3(128), dim3(256), 0, stream>>>(bank, a_ws, wf);
        k_conv<true><<<grid, dim3(256), 0, stream>>>(x, xt, wf, out);
    } else {
        k_mean  <<<dim3(B_SZ * CIN), dim3(64), 0, stream>>>(x, v_ws);
        k_router<<<dim3(B_SZ), dim3(64), 0, stream>>>(v_ws, fc1w, fc1b, fc2w, fc2b, a_ws);
        k_premix<<<dim3(128), dim3(256), 0, stream>>>(bank, a_ws, wf);
        k_conv<false><<<grid, dim3(256), 0, stream>>>(x, wf /*unused*/, wf, out);
    }
}

// Round 4
// 619.487 us; speedup vs baseline: 1.0229x; 1.0229x over previous
//
#include <hip/hip_runtime.h>
#include <stdint.h>

typedef unsigned short u16;
typedef unsigned int   u32;

#define B_SZ  32
#define CIN   256
#define NPIX  3136      // 56*56
#define COUT  256
#define HID   64
#define NBANK 4
#define BANK_SZ 589824  // COUT*CIN*9 per bank (fp32 elements)
#define WF_N  18874368  // premixed elements per half: 32*8*9*8*2*512
#define XT_N  25690112  // pre-split x elements per half: 32*3136*256

// LDS B-plane geometry: [oct 0..3][pos 0..347][8 u16], oct stride padded
#define OCTS  2792      // 348*8 + 8 pad (u16)
#define PLANE 11168     // 4*OCTS (u16)

typedef short bf16x8 __attribute__((ext_vector_type(8)));
typedef float f32x16 __attribute__((ext_vector_type(16)));

struct __align__(16) U4 { u32 x, y, z, w; };
struct __align__(16) F4 { float x, y, z, w; };

__device__ __forceinline__ float bf2f(u16 u) {
    union { u32 i; float f; } v; v.i = ((u32)u) << 16; return v.f;
}
__device__ __forceinline__ u16 f2bf(float f) {
    union { float f; u32 i; } v; v.f = f;
    u32 u = v.i;
    return (u16)((u + 0x7FFFu + ((u >> 16) & 1u)) >> 16);   // RNE
}

// ---------------------------------------------------------------- mean ----
__global__ __launch_bounds__(64) void k_mean(const float* __restrict__ x,
                                             float* __restrict__ vout) {
    int bc = blockIdx.x;
    const F4* p = (const F4*)(x + (size_t)bc * NPIX);
    float s = 0.f;
    for (int o = threadIdx.x; o < 784; o += 64) {
        F4 u = p[o];
        s += u.x + u.y + u.z + u.w;
    }
    #pragma unroll
    for (int off = 32; off > 0; off >>= 1) s += __shfl_down(s, off, 64);
    if (threadIdx.x == 0) vout[bc] = s * (1.0f / 3136.0f);
}

// --------------------------------------------------------------- split ----
// x fp32 [b][ci][pix] -> xt_h/xt_l bf16 [b][pix][ci] (hi, lo at +XT_N).
// grid (49 pix-tiles, 4 ci-chunks of 64, 32 b), 256 thr. LDS 64x65 fp32.
__global__ __launch_bounds__(256) void k_split(const float* __restrict__ x,
        u16* __restrict__ xt) {
    const int ptile = blockIdx.x, cchunk = blockIdx.y, b = blockIdx.z;
    const int pix0 = ptile * 64, ci0 = cchunk * 64;
    const int t = threadIdx.x, lane = t & 63, w = t >> 6;
    __shared__ float ls[64 * 65];
    const float* xb = x + ((size_t)b * CIN + ci0) * NPIX + pix0;
    #pragma unroll
    for (int r = 0; r < 16; ++r) {
        int ci_l = r * 4 + w;
        ls[ci_l * 65 + lane] = xb[(size_t)ci_l * NPIX + lane];
    }
    __syncthreads();
    u16* xth = xt + ((size_t)b * NPIX + pix0) * 256 + ci0;
    #pragma unroll
    for (int rep = 0; rep < 2; ++rep) {
        int item = rep * 256 + t;
        int pix_l = item >> 3, o8 = item & 7;
        u16 eh[8], el[8];
        #pragma unroll
        for (int q = 0; q < 8; ++q) {
            float v = ls[(o8 * 8 + q) * 65 + pix_l];
            u16 h = f2bf(v);
            eh[q] = h;
            el[q] = f2bf(v - bf2f(h));
        }
        U4 uh, ul;
        uh.x = (u32)eh[0] | ((u32)eh[1] << 16);
        uh.y = (u32)eh[2] | ((u32)eh[3] << 16);
        uh.z = (u32)eh[4] | ((u32)eh[5] << 16);
        uh.w = (u32)eh[6] | ((u32)eh[7] << 16);
        ul.x = (u32)el[0] | ((u32)el[1] << 16);
        ul.y = (u32)el[2] | ((u32)el[3] << 16);
        ul.z = (u32)el[4] | ((u32)el[5] << 16);
        ul.w = (u32)el[6] | ((u32)el[7] << 16);
        *(U4*)(xth + (size_t)pix_l * 256 + o8 * 8)        = uh;
        *(U4*)(xth + XT_N + (size_t)pix_l * 256 + o8 * 8) = ul;
    }
}

// -------------------------------------------------------------- router ----
__global__ __launch_bounds__(64) void k_router(const float* __restrict__ v,
        const float* __restrict__ fc1w, const float* __restrict__ fc1b,
        const float* __restrict__ fc2w, const float* __restrict__ fc2b,
        float* __restrict__ aout) {
    int b = blockIdx.x, j = threadIdx.x;
    __shared__ float hl[HID];
    __shared__ float lg[NBANK];
    const float* vb = v + b * CIN;
    float acc = fc1b[j];
    const F4* wrow = (const F4*)(fc1w + j * CIN);
    for (int o = 0; o < 64; ++o) {
        F4 u = wrow[o];
        acc += vb[o * 4 + 0] * u.x + vb[o * 4 + 1] * u.y
             + vb[o * 4 + 2] * u.z + vb[o * 4 + 3] * u.w;
    }
    hl[j] = acc > 0.f ? acc : 0.f;
    __syncthreads();
    if (j < NBANK) {
        float l = fc2b[j];
        for (int t = 0; t < HID; ++t) l += hl[t] * fc2w[j * HID + t];
        lg[j] = l;
    }
    __syncthreads();
    if (j == 0) {
        float m = lg[0];
        for (int k = 1; k < NBANK; ++k) m = fmaxf(m, lg[k]);
        float e[NBANK], se = 0.f;
        for (int k = 0; k < NBANK; ++k) { e[k] = expf(lg[k] - m); se += e[k]; }
        for (int k = 0; k < NBANK; ++k) aout[b * NBANK + k] = e[k] / se;
    }
}

// -------------------------------------------------------------- premix ----
// Wdyn = sum_k a[b][k]*bank[k], fp32 mix -> bf16 hi/lo, 32x32x16 MFMA-A
// layout: wf[half][b][cof32][t][cis][kc][lane][8]
//   co = cof32*32 + (lane&31); ci = cis*32 + kc*16 + (lane>>5)*8 + jj
// grid = (128, 2) blocks (cof32 in [0,8) x cis16 in [0,16); b-halves).
#define PMP 145
__global__ __launch_bounds__(256) void k_premix(const float* __restrict__ bank,
        const float* __restrict__ aws, u16* __restrict__ wf) {
    const int cof   = blockIdx.x >> 4;   // 0..7
    const int cis16 = blockIdx.x & 15;   // 0..15 (16-ci granule)
    const int b0    = blockIdx.y * 16;
    __shared__ float lw[128 * PMP];      // [k*32+co_l][ci_l16*9 + t]
    for (int idx = threadIdx.x; idx < 128 * 144; idx += 256) {
        int s = idx / 144;               // k*32 + co_l
        int e = idx - s * 144;
        int k = s >> 5, co_l = s & 31;
        lw[s * PMP + e] =
            bank[(size_t)(k * COUT + cof * 32 + co_l) * (CIN * 9) + cis16 * 144 + e];
    }
    __syncthreads();
    const int kc = cis16 & 1, cis = cis16 >> 1;
    for (int b = b0; b < b0 + 16; ++b) {
        float a0 = aws[b * 4 + 0], a1 = aws[b * 4 + 1];
        float a2 = aws[b * 4 + 2], a3 = aws[b * 4 + 3];
        for (int o = threadIdx.x; o < 576; o += 256) {   // 9 taps * 64 lanes
            int t = o >> 6, lane = o & 63;
            int m = lane & 31, h5 = lane >> 5;
            u16 ph[8], plo[8];
            #pragma unroll
            for (int jj = 0; jj < 8; ++jj) {
                int ee = (h5 * 8 + jj) * 9 + t;
                float w = a0 * lw[(0 * 32 + m) * PMP + ee]
                        + a1 * lw[(1 * 32 + m) * PMP + ee]
                        + a2 * lw[(2 * 32 + m) * PMP + ee]
                        + a3 * lw[(3 * 32 + m) * PMP + ee];
                u16 h = f2bf(w);
                ph[jj]  = h;
                plo[jj] = f2bf(w - bf2f(h));
            }
            size_t off = ((((size_t)b * 8 + cof) * 9 + t) * 8 + cis) * 1024
                       + (size_t)kc * 512 + (size_t)lane * 8;
            U4 uh, ul;
            uh.x = (u32)ph[0] | ((u32)ph[1] << 16);
            uh.y = (u32)ph[2] | ((u32)ph[3] << 16);
            uh.z = (u32)ph[4] | ((u32)ph[5] << 16);
            uh.w = (u32)ph[6] | ((u32)ph[7] << 16);
            ul.x = (u32)plo[0] | ((u32)plo[1] << 16);
            ul.y = (u32)plo[2] | ((u32)plo[3] << 16);
            ul.z = (u32)plo[4] | ((u32)plo[5] << 16);
            ul.w = (u32)plo[6] | ((u32)plo[7] << 16);
            *(U4*)(wf + off)        = uh;
            *(U4*)(wf + WF_N + off) = ul;
        }
    }
}

// ---------------------------------------------------------------- conv ----
// Implicit GEMM, split-bf16 3-pass: y ~= wh*xh + wh*xl + wl*xh (fp32 acc).
// mfma_f32_32x32x16_bf16. Block 256 thr = 4 waves (2x2 over co x pix),
// block tile 128co x 128pix; per wave 64co x 64pix = 2mf x 2nf f32x16 acc.
// LDS: hi/lo planes, each [oct 0..3][pos 0..347][16B] (oct stride padded):
// B-frag read = consecutive lanes -> contiguous 16B slots => conflict-free.
// SPLIT: staged from pre-split xt via b128 load + ds_write; OOB halo
// pre-zeroed once. !SPLIT: in-kernel fp32 load + split (ws fallback).
template<bool SPLIT>
__global__ __launch_bounds__(256, 2) void k_conv(const float* __restrict__ x,
        const u16* __restrict__ xt,       // pre-split hi; lo at +XT_N
        const u16* __restrict__ wf,       // premixed hi; lo at +WF_N
        float* __restrict__ out) {
    const int pt    = blockIdx.x;   // 0..24 pixel tile (128 px)
    const int coblk = blockIdx.y;   // 0..1  co half (128 co)
    const int b     = blockIdx.z;   // 0..31

    const int tid  = threadIdx.x;
    const int wave = tid >> 6;
    const int lane = tid & 63;
    const int wm = wave >> 1, wn = wave & 1;
    const int m5 = lane & 31, h5 = lane >> 5;

    __shared__ u16 xs[2 * PLANE];   // hi plane @0, lo plane @PLANE

    const int pix0 = pt * 128;
    const int h0   = pix0 / 56;
    const int rlo  = h0 - 1;

    // pre-zero OOB halo slots once (staging never writes them)
    for (int rc = tid; rc < 348; rc += 256) {
        int row = rc / 58, col = rc - row * 58;
        int hin = rlo + row, win = col - 1;
        if (!((unsigned)hin < 56u && (unsigned)win < 56u)) {
            U4 z; z.x = z.y = z.z = z.w = 0;
            #pragma unroll
            for (int o = 0; o < 4; ++o) {
                *(U4*)(&xs[o * OCTS + rc * 8])         = z;
                *(U4*)(&xs[PLANE + o * OCTS + rc * 8]) = z;
            }
        }
    }

    // per-lane B pixel info (nf covers pixels +0, +32)
    int rcb[2], pl[2];
    #pragma unroll
    for (int nf = 0; nf < 2; ++nf) {
        int p = pix0 + wn * 64 + nf * 32 + m5;
        pl[nf] = p;
        int pc = p < NPIX ? p : NPIX - 1;
        int hp = pc / 56, wp = pc - (pc / 56) * 56;
        rcb[nf] = (hp - h0) * 58 + wp;
    }

    const int cof_base = coblk * 4 + wm * 2;
    const u16* xth = xt + (size_t)b * (NPIX * 256);
    const u16* xtl = xth + XT_N;
    const float* xb = x + (size_t)b * CIN * NPIX;

    f32x16 acc[2][2];
    #pragma unroll
    for (int i = 0; i < 2; ++i)
        #pragma unroll
        for (int j = 0; j < 2; ++j)
            #pragma unroll
            for (int r = 0; r < 16; ++r) acc[i][j][r] = 0.f;

    for (int cis = 0; cis < 8; ++cis) {
        __syncthreads();   // prev readers done (iter0: zero-writes ordered)
        // ---- stage 1392 items (348 pos x 4 octets, 16B each) ----
        for (int idx = tid; idx < 1392; idx += 256) {
            int pos  = idx >> 2;
            int soct = idx & 3;
            int row = pos / 58, col = pos - (pos / 58) * 58;
            int hin = rlo + row, win = col - 1;
            if ((unsigned)hin < 56u && (unsigned)win < 56u) {
                if (SPLIT) {
                    size_t gb = (size_t)((hin * 56 + win) * 256 + cis * 32 + soct * 8);
                    *(U4*)(&xs[soct * OCTS + pos * 8])         = *(const U4*)(xth + gb);
                    *(U4*)(&xs[PLANE + soct * OCTS + pos * 8]) = *(const U4*)(xtl + gb);
                } else {
                    const float* g = xb + (size_t)(cis * 32 + soct * 8) * NPIX
                                   + hin * 56 + win;
                    u16 eh[8], el[8];
                    #pragma unroll
                    for (int i = 0; i < 8; ++i) {
                        float v = g[(size_t)i * NPIX];
                        u16 h = f2bf(v);
                        eh[i] = h;
                        el[i] = f2bf(v - bf2f(h));
                    }
                    U4 uh, ul;
                    uh.x = (u32)eh[0] | ((u32)eh[1] << 16);
                    uh.y = (u32)eh[2] | ((u32)eh[3] << 16);
                    uh.z = (u32)eh[4] | ((u32)eh[5] << 16);
                    uh.w = (u32)eh[6] | ((u32)eh[7] << 16);
                    ul.x = (u32)el[0] | ((u32)el[1] << 16);
                    ul.y = (u32)el[2] | ((u32)el[3] << 16);
                    ul.z = (u32)el[4] | ((u32)el[5] << 16);
                    ul.w = (u32)el[6] | ((u32)el[7] << 16);
                    *(U4*)(&xs[soct * OCTS + pos * 8])         = uh;
                    *(U4*)(&xs[PLANE + soct * OCTS + pos * 8]) = ul;
                }
            }
        }
        __syncthreads();

        #pragma unroll
        for (int t = 0; t < 9; ++t) {
            const int ty = t / 3, tx = t - (t / 3) * 3;
            bf16x8 ah[2][2], al[2][2];
            #pragma unroll
            for (int mf = 0; mf < 2; ++mf)
                #pragma unroll
                for (int kc = 0; kc < 2; ++kc) {
                    size_t off = ((((size_t)b * 8 + cof_base + mf) * 9 + t) * 8 + cis) * 1024
                               + (size_t)kc * 512 + (size_t)lane * 8;
                    ah[mf][kc] = *(const bf16x8*)(wf + off);
                    al[mf][kc] = *(const bf16x8*)(wf + WF_N + off);
                }
            #pragma unroll
            for (int nf = 0; nf < 2; ++nf) {
                int rc = rcb[nf] + ty * 58 + tx;
                #pragma unroll
                for (int kc = 0; kc < 2; ++kc) {
                    int eoff = (kc * 2 + h5) * OCTS + rc * 8;
                    bf16x8 bh = *(const bf16x8*)(&xs[eoff]);
                    bf16x8 bl = *(const bf16x8*)(&xs[PLANE + eoff]);
                    #pragma unroll
                    for (int mf = 0; mf < 2; ++mf) {
                        acc[mf][nf] = __builtin_amdgcn_mfma_f32_32x32x16_bf16(
                            ah[mf][kc], bh, acc[mf][nf], 0, 0, 0);
                        acc[mf][nf] = __builtin_amdgcn_mfma_f32_32x32x16_bf16(
                            ah[mf][kc], bl, acc[mf][nf], 0, 0, 0);
                        acc[mf][nf] = __builtin_amdgcn_mfma_f32_32x32x16_bf16(
                            al[mf][kc], bh, acc[mf][nf], 0, 0, 0);
                    }
                }
            }
        }
    }

    // epilogue: 32x32 C/D: col(pixel)=lane&31, row(co)=(r&3)+8*(r>>2)+4*(lane>>5)
    float* ob = out + (size_t)b * COUT * NPIX;
    #pragma unroll
    for (int mf = 0; mf < 2; ++mf) {
        int co0 = coblk * 128 + wm * 64 + mf * 32 + h5 * 4;
        #pragma unroll
        for (int nf = 0; nf < 2; ++nf) {
            int p = pl[nf];
            if (p < NPIX) {
                #pragma unroll
                for (int r = 0; r < 16; ++r) {
                    int co = co0 + (r & 3) + 8 * (r >> 2);
                    ob[(size_t)co * NPIX + p] = acc[mf][nf][r];
                }
            }
        }
    }
}

// -------------------------------------------------------------- launch ----
extern "C" void kernel_launch(void* const* d_in, const int* in_sizes, int n_in,
                              void* d_out, int out_size, void* d_ws, size_t ws_size,
                              hipStream_t stream) {
    const float* x    = (const float*)d_in[0];
    const float* bank = (const float*)d_in[1];
    const float* fc1w = (const float*)d_in[2];
    const float* fc1b = (const float*)d_in[3];
    const float* fc2w = (const float*)d_in[4];
    const float* fc2b = (const float*)d_in[5];
    float* out = (float*)d_out;

    float* a_ws = (float*)d_ws;                 // 128 floats
    float* v_ws = (float*)d_ws + 128;           // 8192 floats
    u16*   wf   = (u16*)((char*)d_ws + 65536);  // 75.5 MB premixed hi/lo
    u16*   xt   = (u16*)((char*)d_ws + 65536 + (size_t)WF_N * 4);  // 102.8 MB

    const size_t need_full = 65536 + (size_t)WF_N * 4 + (size_t)XT_N * 4;
    dim3 grid(25, 2, B_SZ);

    k_mean  <<<dim3(B_SZ * CIN), dim3(64), 0, stream>>>(x, v_ws);
    k_router<<<dim3(B_SZ), dim3(64), 0, stream>>>(v_ws, fc1w, fc1b, fc2w, fc2b, a_ws);
    k_premix<<<dim3(128, 2), dim3(256), 0, stream>>>(bank, a_ws, wf);

    if (ws_size >= need_full) {
        k_split<<<dim3(49, 4, B_SZ), dim3(256), 0, stream>>>(x, xt);
        k_conv<true><<<grid, dim3(256), 0, stream>>>(x, xt, wf, out);
    } else {
        k_conv<false><<<grid, dim3(256), 0, stream>>>(x, xt /*unused*/, wf, out);
    }
}